// Round 6
// baseline (110.734 us; speedup 1.0000x reference)
//
#include <hip/hip_runtime.h>
#include <hip/hip_bf16.h>
#include <math.h>

#define EPS 1e-6f
#define PITCH 72  // bf16 elems per LDS row: 64 K + 8 pad (2-way bank conflict = free)

typedef short s16x8 __attribute__((ext_vector_type(8)));
typedef float f32x4 __attribute__((ext_vector_type(4)));

__device__ __forceinline__ short bf16of(float f) {
  __hip_bfloat16 h = __float2bfloat16(f);
  return __builtin_bit_cast(short, h);
}

// ---------------------------------------------------------------------------
// K1 (MFMA): y[m][p] = sum_c x[img][c][hw] * w1[p][c].   (unchanged, r5)
// ---------------------------------------------------------------------------
__global__ __launch_bounds__(256) void k_conv1x1(const float* __restrict__ x,
                                                 const float* __restrict__ w1,
                                                 float* __restrict__ y) {
  __shared__ __align__(16) short Aw[256 * PITCH];  // [p][k]
  __shared__ __align__(16) short Xs[64 * PITCH];   // [m][k]
  const int t = threadIdx.x;
  const int m0 = blockIdx.x * 64;
  const int img = m0 >> 12, hw0 = m0 & 4095;
  const int lane = t & 63, w = t >> 6;
  const int lrow = lane & 15, lk = (lane >> 4) * 8;
  f32x4 acc[8][2];
#pragma unroll
  for (int i = 0; i < 8; ++i)
#pragma unroll
    for (int j = 0; j < 2; ++j) acc[i][j] = {0.f, 0.f, 0.f, 0.f};

  for (int kk = 0; kk < 128; kk += 64) {
    __syncthreads();
    {
      const float* wp = w1 + (size_t)t * 128 + kk;
#pragma unroll
      for (int q = 0; q < 16; ++q) {
        const float4 v = *(const float4*)(wp + q * 4);
        short4 sv = {bf16of(v.x), bf16of(v.y), bf16of(v.z), bf16of(v.w)};
        *(short4*)(&Aw[t * PITCH + q * 4]) = sv;
      }
    }
    {
      const int m4 = (t & 15) * 4;
      const int cg = (t >> 4) * 4;
      float4 col[4];
#pragma unroll
      for (int cc = 0; cc < 4; ++cc)
        col[cc] = *(const float4*)(x + (size_t)(img * 128 + kk + cg + cc) * 4096 + hw0 + m4);
#pragma unroll
      for (int r = 0; r < 4; ++r) {
        short4 sv = {bf16of(((const float*)&col[0])[r]),
                     bf16of(((const float*)&col[1])[r]),
                     bf16of(((const float*)&col[2])[r]),
                     bf16of(((const float*)&col[3])[r])};
        *(short4*)(&Xs[(m4 + r) * PITCH + cg]) = sv;
      }
    }
    __syncthreads();
#pragma unroll
    for (int ks = 0; ks < 2; ++ks) {
      const int ko = ks * 32 + lk;
      s16x8 bfr[2];
#pragma unroll
      for (int j = 0; j < 2; ++j)
        bfr[j] = *(const s16x8*)(&Xs[(((w >> 1) * 2 + j) * 16 + lrow) * PITCH + ko]);
#pragma unroll
      for (int i = 0; i < 8; ++i) {
        const s16x8 af = *(const s16x8*)(&Aw[(((w & 1) * 8 + i) * 16 + lrow) * PITCH + ko]);
#pragma unroll
        for (int j = 0; j < 2; ++j)
          acc[i][j] = __builtin_amdgcn_mfma_f32_16x16x32_bf16(af, bfr[j], acc[i][j], 0, 0, 0);
      }
    }
  }
#pragma unroll
  for (int i = 0; i < 8; ++i) {
    const int p = ((w & 1) * 8 + i) * 16 + (lane >> 4) * 4;
#pragma unroll
    for (int j = 0; j < 2; ++j) {
      const int m = m0 + ((w >> 1) * 2 + j) * 16 + lrow;
      *(f32x4*)(y + (size_t)m * 256 + p) = acc[i][j];
    }
  }
}

// ---------------------------------------------------------------------------
// K2: depthwise 3x3 SAME + bias, NHWC layout (unchanged).
// ---------------------------------------------------------------------------
__global__ __launch_bounds__(256) void k_dwconv(const float* __restrict__ y,
                                                const float* __restrict__ w3,
                                                const float* __restrict__ b3,
                                                float* __restrict__ xm) {
  __shared__ float wt[9][256];
  __shared__ float bs[256];
  const int t = threadIdx.x;
#pragma unroll
  for (int i = 0; i < 9; ++i) wt[i][t] = w3[t * 9 + i];
  bs[t] = b3[t];
  __syncthreads();
  const int sub = t >> 6;
  const int pq = t & 63;
  const int m = blockIdx.x * 4 + sub;
  const int hw = m & 4095;
  const int h = hw >> 6, ww = hw & 63;
  const int bb = m >> 12;
  float4 acc = *(const float4*)(&bs[pq * 4]);
#pragma unroll
  for (int dy = -1; dy <= 1; ++dy) {
    const int hh = h + dy;
    if (hh < 0 || hh > 63) continue;
#pragma unroll
    for (int dx = -1; dx <= 1; ++dx) {
      const int w2 = ww + dx;
      if (w2 < 0 || w2 > 63) continue;
      const int idx = (dy + 1) * 3 + (dx + 1);
      const float4 v =
          *(const float4*)(y + (size_t)((bb << 12) + (hh << 6) + w2) * 256 + pq * 4);
      const float4 wv = *(const float4*)(&wt[idx][pq * 4]);
      acc.x += v.x * wv.x;
      acc.y += v.y * wv.y;
      acc.z += v.z * wv.z;
      acc.w += v.w * wv.w;
    }
  }
  *(float4*)(xm + (size_t)m * 256 + pq * 4) = acc;
}

// ---------------------------------------------------------------------------
// K3 (fused): lower-GEMM -> xl tile in LDS -> per-wave fast EM -> feat +
// pool partials. LDS union: {Aw,Xs} (GEMM phase) / {xlL, psL, pmL, sflag}
// (EM phase). Asymmetric pixels: xl row -> xl_fb, flag[bid]=1; em_slow +
// pool_fix clean up (never taken for uniform[0,1) binit).
// ---------------------------------------------------------------------------
__global__ __launch_bounds__(256, 2) void k_lower_em(
    const float* __restrict__ xm, const float* __restrict__ lw,
    const float* __restrict__ lb, const float* __restrict__ binit,
    float* feat, float* __restrict__ xl_fb, float* __restrict__ psum,
    float* __restrict__ pmax, int* __restrict__ flag) {
  __shared__ __align__(16) char smem[74768];
  short* Aw = (short*)smem;              // 256*72*2 = 36864 B
  short* Xs = (short*)(smem + 36864);    // 64*72*2  =  9216 B
  float* xlL = (float*)smem;             // 64*260*4 = 66560 B (reuse)
  float* psL = (float*)(smem + 66560);   // 4*256*4
  float* pmL = (float*)(smem + 70656);   // 4*256*4
  int* sflag = (int*)(smem + 74752);
  const int t = threadIdx.x;
  const int m0 = blockIdx.x * 64;
  const int lane = t & 63, w = t >> 6;
  const int lrow = lane & 15, lk = (lane >> 4) * 8;
  f32x4 acc[8][2];
#pragma unroll
  for (int i = 0; i < 8; ++i)
#pragma unroll
    for (int j = 0; j < 2; ++j) acc[i][j] = {0.f, 0.f, 0.f, 0.f};

  for (int kk = 0; kk < 256; kk += 64) {
    __syncthreads();
    {  // stage lw: row n = t
      const float* wp = lw + (size_t)t * 256 + kk;
#pragma unroll
      for (int q = 0; q < 16; ++q) {
        const float4 v = *(const float4*)(wp + q * 4);
        short4 sv = {bf16of(v.x), bf16of(v.y), bf16of(v.z), bf16of(v.w)};
        *(short4*)(&Aw[t * PITCH + q * 4]) = sv;
      }
    }
    {  // stage xm
      const int m = t & 63, q = t >> 6;
      const float* xp = xm + (size_t)(m0 + m) * 256 + kk + q * 16;
#pragma unroll
      for (int jj = 0; jj < 4; ++jj) {
        const float4 v = *(const float4*)(xp + jj * 4);
        short4 sv = {bf16of(v.x), bf16of(v.y), bf16of(v.z), bf16of(v.w)};
        *(short4*)(&Xs[m * PITCH + q * 16 + jj * 4]) = sv;
      }
    }
    __syncthreads();
#pragma unroll
    for (int ks = 0; ks < 2; ++ks) {
      const int ko = ks * 32 + lk;
      s16x8 bfr[2];
#pragma unroll
      for (int j = 0; j < 2; ++j)
        bfr[j] = *(const s16x8*)(&Xs[(((w >> 1) * 2 + j) * 16 + lrow) * PITCH + ko]);
#pragma unroll
      for (int i = 0; i < 8; ++i) {
        const s16x8 af = *(const s16x8*)(&Aw[(((w & 1) * 8 + i) * 16 + lrow) * PITCH + ko]);
#pragma unroll
        for (int j = 0; j < 2; ++j)
          acc[i][j] = __builtin_amdgcn_mfma_f32_16x16x32_bf16(af, bfr[j], acc[i][j], 0, 0, 0);
      }
    }
  }
  __syncthreads();  // all LDS reads done -> safe to overwrite staging with xlL
  if (t == 0) *sflag = 0;
#pragma unroll
  for (int i = 0; i < 8; ++i) {
    const int n = ((w & 1) * 8 + i) * 16 + (lane >> 4) * 4;
    const float4 bias = *(const float4*)(lb + n);
#pragma unroll
    for (int j = 0; j < 2; ++j) {
      const int mr = ((w >> 1) * 2 + j) * 16 + lrow;
      f32x4 v = acc[i][j];
      v.x = fmaxf(v.x + bias.x, 0.f);
      v.y = fmaxf(v.y + bias.y, 0.f);
      v.z = fmaxf(v.z + bias.z, 0.f);
      v.w = fmaxf(v.w + bias.w, 0.f);
      *(f32x4*)(&xlL[mr * 260 + n]) = v;
    }
  }
  __syncthreads();

  // ---- EM phase: wave w handles rows w*16 .. w*16+15 ----
  float ps4[4] = {0.f, 0.f, 0.f, 0.f};
  float pm4[4] = {-1e30f, -1e30f, -1e30f, -1e30f};
  for (int pi = 0; pi < 16; ++pi) {
    const int mr = w * 16 + pi;
    const int m = m0 + mr;
    const float bv0 = binit[m * 16 + (lane & 15)];
    const float bn0 = bv0 / fmaxf(fabsf(bv0), 1e-12f);
    const f32x4 s4v = *(const f32x4*)(&xlL[mr * 260 + lane * 4]);
    if (!__all(bn0 == 1.0f)) {  // asymmetric: defer to em_slow/pool_fix
      *(f32x4*)(xl_fb + (size_t)m * 256 + lane * 4) = s4v;
      if (lane == 0) *sflag = 1;
      continue;
    }
    const float s[4] = {s4v.x, s4v.y, s4v.z, s4v.w};
    float C[4] = {0.0625f, 0.0625f, 0.0625f, 0.0625f};
    float Bv = 1.f;
    for (int step = 0; step < 6; ++step) {
      const float k1 = 16.f * Bv * Bv;
      float pnum = 0.f, psq = 0.f;
#pragma unroll
      for (int i = 0; i < 4; ++i) {
        const float den = fmaf(C[i], k1, EPS);
        const float cn = C[i] * (s[i] * Bv) * __builtin_amdgcn_rcpf(den);
        C[i] = cn;
        pnum = fmaf(s[i], cn, pnum);
        psq = fmaf(cn, cn, psq);
      }
#pragma unroll
      for (int d = 1; d < 64; d <<= 1) {
        pnum += __shfl_xor(pnum, d, 64);
        psq += __shfl_xor(psq, d, 64);
      }
      const float den2 = fmaf(16.f * Bv, psq, EPS);
      Bv = Bv * pnum * __builtin_amdgcn_rcpf(den2);
    }
    const float4 xm4 = *(const float4*)(xm + (size_t)m * 256 + lane * 4);
    const float xmv[4] = {xm4.x, xm4.y, xm4.z, xm4.w};
    const float k1 = 16.f * Bv * Bv;
    float o[4];
#pragma unroll
    for (int i = 0; i < 4; ++i) {
      const float den = fmaf(C[i], k1, EPS);
      const float cn = C[i] * (s[i] * Bv) * __builtin_amdgcn_rcpf(den);
      const float xr = 16.f * Bv * cn;
      o[i] = fmaxf(xmv[i] + xr, 0.f);
      ps4[i] += o[i];
      pm4[i] = fmaxf(pm4[i], o[i]);
    }
    const f32x4 outv = {o[0], o[1], o[2], o[3]};
    *(f32x4*)(feat + (size_t)m * 256 + lane * 4) = outv;
  }
  // ---- pool partial combine across the 4 waves ----
#pragma unroll
  for (int i = 0; i < 4; ++i) {
    psL[w * 256 + lane * 4 + i] = ps4[i];
    pmL[w * 256 + lane * 4 + i] = pm4[i];
  }
  __syncthreads();
  const float sv = psL[t] + psL[256 + t] + psL[512 + t] + psL[768 + t];
  const float mv = fmaxf(fmaxf(pmL[t], pmL[256 + t]), fmaxf(pmL[512 + t], pmL[768 + t]));
  psum[(size_t)blockIdx.x * 256 + t] = sv;
  pmax[(size_t)blockIdx.x * 256 + t] = mv;
  if (t == 0) flag[blockIdx.x] = *sflag;
}

// ---------------------------------------------------------------------------
// K4b: general EM fallback, flag-gated (xl from fallback buffer).
// ---------------------------------------------------------------------------
__global__ __launch_bounds__(256, 2) void k_em_slow(const float* xl,
                                                    const float* __restrict__ binit,
                                                    const float* __restrict__ xmp,
                                                    float* feat,
                                                    const int* __restrict__ flag) {
  if (flag[blockIdx.x >> 4] == 0) return;
  const int lane = threadIdx.x & 63;
  const int m = blockIdx.x * 4 + (threadIdx.x >> 6);
  const float bv0 = binit[m * 16 + (lane & 15)];
  const float bn0 = bv0 / fmaxf(fabsf(bv0), 1e-12f);
  if (__all(bn0 == 1.0f)) return;
  const float4 s4 = *(const float4*)(xl + (size_t)m * 256 + lane * 4);
  const float s[4] = {s4.x, s4.y, s4.z, s4.w};
  float b[16];
#pragma unroll
  for (int r = 0; r < 16; ++r) {
    const float v = binit[m * 16 + r];
    b[r] = v / fmaxf(fabsf(v), 1e-12f);
  }
  float c[4][16];
#pragma unroll
  for (int i = 0; i < 4; ++i) {
    float mx = s[i] * b[0];
#pragma unroll
    for (int r = 1; r < 16; ++r) mx = fmaxf(mx, s[i] * b[r]);
    float sum = 0.f;
#pragma unroll
    for (int r = 0; r < 16; ++r) {
      const float e = __expf(s[i] * b[r] - mx);
      c[i][r] = e;
      sum += e;
    }
    const float inv = __fdividef(1.f, sum);
#pragma unroll
    for (int r = 0; r < 16; ++r) c[i][r] *= inv;
  }
  for (int step = 0; step < 6; ++step) {
    float red[32];
#pragma unroll
    for (int r = 0; r < 32; ++r) red[r] = 0.f;
#pragma unroll
    for (int i = 0; i < 4; ++i) {
      float tt = 0.f;
#pragma unroll
      for (int r = 0; r < 16; ++r) tt += c[i][r] * b[r];
      float tp = 0.f;
#pragma unroll
      for (int r = 0; r < 16; ++r) {
        const float cn = c[i][r] * (s[i] * b[r]) * __frcp_rn(tt * b[r] + EPS);
        c[i][r] = cn;
        tp += cn * b[r];
        red[r] += s[i] * cn;
      }
#pragma unroll
      for (int r = 0; r < 16; ++r) red[16 + r] += tp * c[i][r];
    }
    int cnt = 32;
#pragma unroll
    for (int k = 4; k >= 0; --k) {
      const int d = 1 << k;
      const bool up = (lane >> k) & 1;
      const int half = cnt >> 1;
#pragma unroll
      for (int j = 0; j < half; ++j) {
        const float lo = red[j], hi = red[j + half];
        const float send = up ? lo : hi;
        const float recv = __shfl_xor(send, d, 64);
        red[j] = (up ? hi : lo) + recv;
      }
      cnt = half;
    }
    float S = red[0] + __shfl_xor(red[0], 32, 64);
    const float dpart = __shfl_xor(S, 16, 64);
    const float q = S * __frcp_rn(dpart + EPS);
#pragma unroll
    for (int r = 0; r < 16; ++r) b[r] *= __shfl(q, r, 64);
  }
  const float4 xm4 = *(const float4*)(xmp + (size_t)m * 256 + lane * 4);
  const float xmv[4] = {xm4.x, xm4.y, xm4.z, xm4.w};
  float o4[4];
#pragma unroll
  for (int i = 0; i < 4; ++i) {
    float tt = 0.f;
#pragma unroll
    for (int r = 0; r < 16; ++r) tt += c[i][r] * b[r];
    float xr = 0.f;
#pragma unroll
    for (int r = 0; r < 16; ++r) {
      const float cn = c[i][r] * (s[i] * b[r]) * __frcp_rn(tt * b[r] + EPS);
      xr += b[r] * cn;
    }
    o4[i] = fmaxf(xmv[i] + xr, 0.f);
  }
  const float4 outv = {o4[0], o4[1], o4[2], o4[3]};
  *(float4*)(feat + (size_t)m * 256 + lane * 4) = outv;
}

// ---------------------------------------------------------------------------
// K5: pool fix — re-derives partials for flagged blocks only.
// ---------------------------------------------------------------------------
__global__ __launch_bounds__(256) void k_pool_fix(const float* __restrict__ feat,
                                                  const int* __restrict__ flag,
                                                  float* __restrict__ psum,
                                                  float* __restrict__ pmax) {
  const int bid = blockIdx.x;
  if (flag[bid] == 0) return;
  const int t = threadIdx.x;
  const float* fp = feat + (size_t)bid * 64 * 256 + t;
  float sum = 0.f, mx = -1e30f;
#pragma unroll 8
  for (int r = 0; r < 64; ++r) {
    const float v = fp[(size_t)r * 256];
    sum += v;
    mx = fmaxf(mx, v);
  }
  psum[(size_t)bid * 256 + t] = sum;
  pmax[(size_t)bid * 256 + t] = mx;
}

// ---------------------------------------------------------------------------
// K6: finish pooling + channel-attention MLP + sigmoid (unchanged).
// ---------------------------------------------------------------------------
__global__ __launch_bounds__(256) void k_att(const float* __restrict__ psum,
                                             const float* __restrict__ pmax,
                                             const float* __restrict__ ca1,
                                             const float* __restrict__ ca2,
                                             float* __restrict__ attv,
                                             float* __restrict__ out_att) {
  __shared__ float sA[256], sM[256], sH[64];
  const int t = threadIdx.x;
  const int b = blockIdx.x;
  float sum = 0.f, mx = -1e30f;
#pragma unroll 8
  for (int ch = 0; ch < 64; ++ch) {
    sum += psum[(size_t)(b * 64 + ch) * 256 + t];
    mx = fmaxf(mx, pmax[(size_t)(b * 64 + ch) * 256 + t]);
  }
  sA[t] = sum * (1.0f / 4096.0f);
  sM[t] = mx;
  __syncthreads();
  if (t < 64) {
    float ha = 0.f, hm = 0.f;
#pragma unroll 8
    for (int p = 0; p < 256; ++p) {
      const float w = ca1[t * 256 + p];
      ha += sA[p] * w;
      hm += sM[p] * w;
    }
    sH[t] = fmaxf(ha, 0.f) + fmaxf(hm, 0.f);
  }
  __syncthreads();
  float logit = 0.f;
#pragma unroll 8
  for (int a = 0; a < 64; ++a) logit += sH[a] * ca2[t * 64 + a];
  const float av = 1.0f / (1.0f + expf(-logit));
  attv[b * 256 + t] = av;
  out_att[b * 256 + t] = av;
}

// ---------------------------------------------------------------------------
// K7 (MFMA): out = (feat*att) @ fw^T + fb   (unchanged, r5)
// ---------------------------------------------------------------------------
__global__ __launch_bounds__(256) void k_fc(const float* __restrict__ feat,
                                            const float* __restrict__ attv,
                                            const float* __restrict__ fw,
                                            const float* __restrict__ fb,
                                            float* __restrict__ out) {
  __shared__ __align__(16) short Fs[64 * PITCH];   // [m][k]
  __shared__ __align__(16) short Ws[128 * PITCH];  // [o][k]
  const int t = threadIdx.x;
  const int m0 = blockIdx.x * 64;
  const int img = m0 >> 12, hw0 = m0 & 4095;
  const int lane = t & 63, w = t >> 6;
  const int lrow = lane & 15, lk = (lane >> 4) * 8;
  f32x4 acc[2][4];
#pragma unroll
  for (int i = 0; i < 2; ++i)
#pragma unroll
    for (int j = 0; j < 4; ++j) acc[i][j] = {0.f, 0.f, 0.f, 0.f};

  for (int kk = 0; kk < 256; kk += 64) {
    __syncthreads();
    {
      const int m = t & 63, q = t >> 6;
      const float* fp = feat + (size_t)(m0 + m) * 256 + kk + q * 16;
      const float* ap = attv + img * 256 + kk + q * 16;
#pragma unroll
      for (int jj = 0; jj < 4; ++jj) {
        const float4 v = *(const float4*)(fp + jj * 4);
        const float4 a = *(const float4*)(ap + jj * 4);
        short4 sv = {bf16of(v.x * a.x), bf16of(v.y * a.y), bf16of(v.z * a.z),
                     bf16of(v.w * a.w)};
        *(short4*)(&Fs[m * PITCH + q * 16 + jj * 4]) = sv;
      }
    }
    {
      const int o = t & 127, q = t >> 7;
      const float* wp = fw + (size_t)o * 256 + kk + q * 32;
#pragma unroll
      for (int jj = 0; jj < 8; ++jj) {
        const float4 v = *(const float4*)(wp + jj * 4);
        short4 sv = {bf16of(v.x), bf16of(v.y), bf16of(v.z), bf16of(v.w)};
        *(short4*)(&Ws[o * PITCH + q * 32 + jj * 4]) = sv;
      }
    }
    __syncthreads();
#pragma unroll
    for (int ks = 0; ks < 2; ++ks) {
      const int ko = ks * 32 + lk;
      s16x8 af[2];
#pragma unroll
      for (int i = 0; i < 2; ++i)
        af[i] = *(const s16x8*)(&Fs[(((w & 1) * 2 + i) * 16 + lrow) * PITCH + ko]);
#pragma unroll
      for (int j = 0; j < 4; ++j) {
        const s16x8 bfr = *(const s16x8*)(&Ws[(((w >> 1) * 4 + j) * 16 + lrow) * PITCH + ko]);
#pragma unroll
        for (int i = 0; i < 2; ++i)
          acc[i][j] = __builtin_amdgcn_mfma_f32_16x16x32_bf16(af[i], bfr, acc[i][j], 0, 0, 0);
      }
    }
  }
#pragma unroll
  for (int j = 0; j < 4; ++j) {
    const int o = ((w >> 1) * 4 + j) * 16 + lrow;
    const float bias = fb[o];
#pragma unroll
    for (int i = 0; i < 2; ++i) {
      const int hw = hw0 + ((w & 1) * 2 + i) * 16 + (lane >> 4) * 4;
      f32x4 v = acc[i][j];
      v.x += bias;
      v.y += bias;
      v.z += bias;
      v.w += bias;
      *(f32x4*)(out + (size_t)img * 524288 + (size_t)o * 4096 + hw) = v;
    }
  }
}

extern "C" void kernel_launch(void* const* d_in, const int* in_sizes, int n_in,
                              void* d_out, int out_size, void* d_ws, size_t ws_size,
                              hipStream_t stream) {
  const float* x = (const float*)d_in[0];
  const float* w1 = (const float*)d_in[1];
  const float* w3 = (const float*)d_in[2];
  const float* b3 = (const float*)d_in[3];
  const float* lw = (const float*)d_in[4];
  const float* lb = (const float*)d_in[5];
  const float* ca1 = (const float*)d_in[6];
  const float* ca2 = (const float*)d_in[7];
  const float* fw = (const float*)d_in[8];
  const float* fb = (const float*)d_in[9];
  const float* binit = (const float*)d_in[10];

  float* ws = (float*)d_ws;
  float* bufA = ws;             // y -> feat        (M*256)
  float* bufB = ws + 4194304;   // xm               (M*256)
  float* bufC = ws + 8388608;   // xl fallback      (M*256)
  float* psum = ws + 12582912;  // 256*256
  float* pmax = psum + 65536;
  float* attv = pmax + 65536;   // 1024
  int* flag = (int*)(attv + 1024);  // 256
  float* out = (float*)d_out;
  float* out_att = out + 2097152;

  const dim3 blk(256);
  k_conv1x1<<<dim3(256), blk, 0, stream>>>(x, w1, bufA);
  k_dwconv<<<dim3(4096), blk, 0, stream>>>(bufA, w3, b3, bufB);
  k_lower_em<<<dim3(256), blk, 0, stream>>>(bufB, lw, lb, binit, bufA, bufC,
                                            psum, pmax, flag);
  k_em_slow<<<dim3(4096), blk, 0, stream>>>(bufC, binit, bufB, bufA, flag);
  k_pool_fix<<<dim3(256), blk, 0, stream>>>(bufA, flag, psum, pmax);
  k_att<<<dim3(4), blk, 0, stream>>>(psum, pmax, ca1, ca2, attv, out_att);
  k_fc<<<dim3(256), blk, 0, stream>>>(bufA, attv, fw, fb, out);
}

// Round 7
// 94.450 us; speedup vs baseline: 1.1724x; 1.1724x over previous
//
#include <hip/hip_runtime.h>
#include <hip/hip_bf16.h>
#include <math.h>

#define EPS 1e-6f
#define PITCH 72  // bf16 elems per LDS row: 64 K + 8 pad (2-way bank conflict = free)

typedef short s16x8 __attribute__((ext_vector_type(8)));
typedef float f32x4 __attribute__((ext_vector_type(4)));

__device__ __forceinline__ short bf16of(float f) {
  __hip_bfloat16 h = __float2bfloat16(f);
  return __builtin_bit_cast(short, h);
}
__device__ __forceinline__ float f32of(unsigned short u) {
  unsigned int x = ((unsigned int)u) << 16;
  return __builtin_bit_cast(float, x);
}

// ---------------------------------------------------------------------------
// K1 (MFMA): y[m][p] = sum_c x[img][c][hw] * w1[p][c].  Output bf16.
// ---------------------------------------------------------------------------
__global__ __launch_bounds__(256) void k_conv1x1(const float* __restrict__ x,
                                                 const float* __restrict__ w1,
                                                 short* __restrict__ ybf) {
  __shared__ __align__(16) short Aw[256 * PITCH];  // [p][k]
  __shared__ __align__(16) short Xs[64 * PITCH];   // [m][k]
  const int t = threadIdx.x;
  const int m0 = blockIdx.x * 64;
  const int img = m0 >> 12, hw0 = m0 & 4095;
  const int lane = t & 63, w = t >> 6;
  const int lrow = lane & 15, lk = (lane >> 4) * 8;
  f32x4 acc[8][2];
#pragma unroll
  for (int i = 0; i < 8; ++i)
#pragma unroll
    for (int j = 0; j < 2; ++j) acc[i][j] = {0.f, 0.f, 0.f, 0.f};

  for (int kk = 0; kk < 128; kk += 64) {
    __syncthreads();
    {
      const float* wp = w1 + (size_t)t * 128 + kk;
#pragma unroll
      for (int q = 0; q < 16; ++q) {
        const float4 v = *(const float4*)(wp + q * 4);
        short4 sv = {bf16of(v.x), bf16of(v.y), bf16of(v.z), bf16of(v.w)};
        *(short4*)(&Aw[t * PITCH + q * 4]) = sv;
      }
    }
    {
      const int m4 = (t & 15) * 4;
      const int cg = (t >> 4) * 4;
      float4 col[4];
#pragma unroll
      for (int cc = 0; cc < 4; ++cc)
        col[cc] = *(const float4*)(x + (size_t)(img * 128 + kk + cg + cc) * 4096 + hw0 + m4);
#pragma unroll
      for (int r = 0; r < 4; ++r) {
        short4 sv = {bf16of(((const float*)&col[0])[r]),
                     bf16of(((const float*)&col[1])[r]),
                     bf16of(((const float*)&col[2])[r]),
                     bf16of(((const float*)&col[3])[r])};
        *(short4*)(&Xs[(m4 + r) * PITCH + cg]) = sv;
      }
    }
    __syncthreads();
#pragma unroll
    for (int ks = 0; ks < 2; ++ks) {
      const int ko = ks * 32 + lk;
      s16x8 bfr[2];
#pragma unroll
      for (int j = 0; j < 2; ++j)
        bfr[j] = *(const s16x8*)(&Xs[(((w >> 1) * 2 + j) * 16 + lrow) * PITCH + ko]);
#pragma unroll
      for (int i = 0; i < 8; ++i) {
        const s16x8 af = *(const s16x8*)(&Aw[(((w & 1) * 8 + i) * 16 + lrow) * PITCH + ko]);
#pragma unroll
        for (int j = 0; j < 2; ++j)
          acc[i][j] = __builtin_amdgcn_mfma_f32_16x16x32_bf16(af, bfr[j], acc[i][j], 0, 0, 0);
      }
    }
  }
#pragma unroll
  for (int i = 0; i < 8; ++i) {
    const int p = ((w & 1) * 8 + i) * 16 + (lane >> 4) * 4;
#pragma unroll
    for (int j = 0; j < 2; ++j) {
      const int m = m0 + ((w >> 1) * 2 + j) * 16 + lrow;
      const f32x4 v = acc[i][j];
      short4 sv = {bf16of(v.x), bf16of(v.y), bf16of(v.z), bf16of(v.w)};
      *(short4*)(ybf + (size_t)m * 256 + p) = sv;
    }
  }
}

// ---------------------------------------------------------------------------
// K2: depthwise 3x3 SAME + bias; bf16 input, fp32 output.
// ---------------------------------------------------------------------------
__global__ __launch_bounds__(256) void k_dwconv(const unsigned short* __restrict__ ybf,
                                                const float* __restrict__ w3,
                                                const float* __restrict__ b3,
                                                float* __restrict__ xm) {
  __shared__ float wt[9][256];
  __shared__ float bs[256];
  const int t = threadIdx.x;
#pragma unroll
  for (int i = 0; i < 9; ++i) wt[i][t] = w3[t * 9 + i];
  bs[t] = b3[t];
  __syncthreads();
  const int sub = t >> 6;
  const int pq = t & 63;
  const int m = blockIdx.x * 4 + sub;
  const int hw = m & 4095;
  const int h = hw >> 6, ww = hw & 63;
  const int bb = m >> 12;
  float4 acc = *(const float4*)(&bs[pq * 4]);
#pragma unroll
  for (int dy = -1; dy <= 1; ++dy) {
    const int hh = h + dy;
    if (hh < 0 || hh > 63) continue;
#pragma unroll
    for (int dx = -1; dx <= 1; ++dx) {
      const int w2 = ww + dx;
      if (w2 < 0 || w2 > 63) continue;
      const int idx = (dy + 1) * 3 + (dx + 1);
      const ushort4 v =
          *(const ushort4*)(ybf + (size_t)((bb << 12) + (hh << 6) + w2) * 256 + pq * 4);
      const float4 wv = *(const float4*)(&wt[idx][pq * 4]);
      acc.x += f32of(v.x) * wv.x;
      acc.y += f32of(v.y) * wv.y;
      acc.z += f32of(v.z) * wv.z;
      acc.w += f32of(v.w) * wv.w;
    }
  }
  *(float4*)(xm + (size_t)m * 256 + pq * 4) = acc;
}

// ---------------------------------------------------------------------------
// K3 (MFMA): xl = relu(xm @ lw^T + lb), fp32 out (unchanged from r5).
// ---------------------------------------------------------------------------
__global__ __launch_bounds__(256) void k_lower(const float* __restrict__ xm,
                                               const float* __restrict__ lw,
                                               const float* __restrict__ lb,
                                               float* __restrict__ xl) {
  __shared__ __align__(16) short Aw[256 * PITCH];
  __shared__ __align__(16) short Xs[64 * PITCH];
  const int t = threadIdx.x;
  const int m0 = blockIdx.x * 64;
  const int lane = t & 63, w = t >> 6;
  const int lrow = lane & 15, lk = (lane >> 4) * 8;
  f32x4 acc[8][2];
#pragma unroll
  for (int i = 0; i < 8; ++i)
#pragma unroll
    for (int j = 0; j < 2; ++j) acc[i][j] = {0.f, 0.f, 0.f, 0.f};

  for (int kk = 0; kk < 256; kk += 64) {
    __syncthreads();
    {
      const float* wp = lw + (size_t)t * 256 + kk;
#pragma unroll
      for (int q = 0; q < 16; ++q) {
        const float4 v = *(const float4*)(wp + q * 4);
        short4 sv = {bf16of(v.x), bf16of(v.y), bf16of(v.z), bf16of(v.w)};
        *(short4*)(&Aw[t * PITCH + q * 4]) = sv;
      }
    }
    {
      const int m = t & 63, q = t >> 6;
      const float* xp = xm + (size_t)(m0 + m) * 256 + kk + q * 16;
#pragma unroll
      for (int jj = 0; jj < 4; ++jj) {
        const float4 v = *(const float4*)(xp + jj * 4);
        short4 sv = {bf16of(v.x), bf16of(v.y), bf16of(v.z), bf16of(v.w)};
        *(short4*)(&Xs[m * PITCH + q * 16 + jj * 4]) = sv;
      }
    }
    __syncthreads();
#pragma unroll
    for (int ks = 0; ks < 2; ++ks) {
      const int ko = ks * 32 + lk;
      s16x8 bfr[2];
#pragma unroll
      for (int j = 0; j < 2; ++j)
        bfr[j] = *(const s16x8*)(&Xs[(((w >> 1) * 2 + j) * 16 + lrow) * PITCH + ko]);
#pragma unroll
      for (int i = 0; i < 8; ++i) {
        const s16x8 af = *(const s16x8*)(&Aw[(((w & 1) * 8 + i) * 16 + lrow) * PITCH + ko]);
#pragma unroll
        for (int j = 0; j < 2; ++j)
          acc[i][j] = __builtin_amdgcn_mfma_f32_16x16x32_bf16(af, bfr[j], acc[i][j], 0, 0, 0);
      }
    }
  }
#pragma unroll
  for (int i = 0; i < 8; ++i) {
    const int n = ((w & 1) * 8 + i) * 16 + (lane >> 4) * 4;
    const float4 bias = *(const float4*)(lb + n);
#pragma unroll
    for (int j = 0; j < 2; ++j) {
      const int m = m0 + ((w >> 1) * 2 + j) * 16 + lrow;
      f32x4 v = acc[i][j];
      v.x = fmaxf(v.x + bias.x, 0.f);
      v.y = fmaxf(v.y + bias.y, 0.f);
      v.z = fmaxf(v.z + bias.z, 0.f);
      v.w = fmaxf(v.w + bias.w, 0.f);
      *(f32x4*)(xl + (size_t)m * 256 + n) = v;
    }
  }
}

// ---------------------------------------------------------------------------
// K4a: fast EM, 16 px/block (4/wave, lockstep ILP-4), fused pooling.
// Writes feat bf16 + per-chunk psum/pmax partials (fp32, pre-rounding).
// Asymmetric chunk -> flag=1, skip (slowfix recomputes whole chunk).
// ---------------------------------------------------------------------------
__global__ __launch_bounds__(256) void k_em_fast(const float* __restrict__ xl,
                                                 const float* __restrict__ binit,
                                                 const float* __restrict__ xm,
                                                 short* __restrict__ featb,
                                                 float* __restrict__ psum,
                                                 float* __restrict__ pmax,
                                                 int* __restrict__ flag) {
  __shared__ float psL[1024], pmL[1024];
  __shared__ int sflag;
  const int t = threadIdx.x;
  const int lane = t & 63, w = t >> 6;
  const int bid = blockIdx.x;
  const int m0 = bid * 16 + w * 4;
  bool asym = false;
#pragma unroll
  for (int p = 0; p < 4; ++p) {
    const float bv = binit[(size_t)(m0 + p) * 16 + (lane & 15)];
    const float bn = bv / fmaxf(fabsf(bv), 1e-12f);
    asym |= !__all(bn == 1.0f);
  }
  if (t == 0) sflag = 0;
  __syncthreads();
  if (asym && lane == 0) sflag = 1;
  __syncthreads();
  if (sflag) {
    if (t == 0) flag[bid] = 1;
    return;
  }

  float s[4][4], C[4][4], Bv[4];
#pragma unroll
  for (int p = 0; p < 4; ++p) {
    const f32x4 s4 = *(const f32x4*)(xl + (size_t)(m0 + p) * 256 + lane * 4);
    s[p][0] = s4.x;
    s[p][1] = s4.y;
    s[p][2] = s4.z;
    s[p][3] = s4.w;
    Bv[p] = 1.f;
#pragma unroll
    for (int i = 0; i < 4; ++i) C[p][i] = 0.0625f;
  }
  for (int step = 0; step < 6; ++step) {
    float pnum[4], psq[4];
#pragma unroll
    for (int p = 0; p < 4; ++p) {
      const float k1 = 16.f * Bv[p] * Bv[p];
      pnum[p] = 0.f;
      psq[p] = 0.f;
#pragma unroll
      for (int i = 0; i < 4; ++i) {
        const float den = fmaf(C[p][i], k1, EPS);
        const float cn = C[p][i] * (s[p][i] * Bv[p]) * __builtin_amdgcn_rcpf(den);
        C[p][i] = cn;
        pnum[p] = fmaf(s[p][i], cn, pnum[p]);
        psq[p] = fmaf(cn, cn, psq[p]);
      }
    }
#pragma unroll
    for (int d = 1; d < 64; d <<= 1) {
#pragma unroll
      for (int p = 0; p < 4; ++p) {
        pnum[p] += __shfl_xor(pnum[p], d, 64);
        psq[p] += __shfl_xor(psq[p], d, 64);
      }
    }
#pragma unroll
    for (int p = 0; p < 4; ++p)
      Bv[p] = Bv[p] * pnum[p] *
              __builtin_amdgcn_rcpf(fmaf(16.f * Bv[p], psq[p], EPS));
  }
  float ps4[4] = {0.f, 0.f, 0.f, 0.f};
  float pm4[4] = {-1e30f, -1e30f, -1e30f, -1e30f};
#pragma unroll
  for (int p = 0; p < 4; ++p) {
    const float4 xm4 = *(const float4*)(xm + (size_t)(m0 + p) * 256 + lane * 4);
    const float xmv[4] = {xm4.x, xm4.y, xm4.z, xm4.w};
    const float k1 = 16.f * Bv[p] * Bv[p];
    float o[4];
#pragma unroll
    for (int i = 0; i < 4; ++i) {
      const float den = fmaf(C[p][i], k1, EPS);
      const float cn = C[p][i] * (s[p][i] * Bv[p]) * __builtin_amdgcn_rcpf(den);
      const float xr = 16.f * Bv[p] * cn;
      o[i] = fmaxf(xmv[i] + xr, 0.f);
      ps4[i] += o[i];
      pm4[i] = fmaxf(pm4[i], o[i]);
    }
    short4 sv = {bf16of(o[0]), bf16of(o[1]), bf16of(o[2]), bf16of(o[3])};
    *(short4*)(featb + (size_t)(m0 + p) * 256 + lane * 4) = sv;
  }
#pragma unroll
  for (int i = 0; i < 4; ++i) {
    psL[w * 256 + lane * 4 + i] = ps4[i];
    pmL[w * 256 + lane * 4 + i] = pm4[i];
  }
  __syncthreads();
  const float sv = psL[t] + psL[256 + t] + psL[512 + t] + psL[768 + t];
  const float mv =
      fmaxf(fmaxf(pmL[t], pmL[256 + t]), fmaxf(pmL[512 + t], pmL[768 + t]));
  psum[(size_t)bid * 256 + t] = sv;
  pmax[(size_t)bid * 256 + t] = mv;
  if (t == 0) flag[bid] = 0;
}

// ---------------------------------------------------------------------------
// K4b: flag-gated general-EM recompute of a whole 16-pixel chunk (feat bf16
// + pool partials). Never taken for uniform[0,1) binit.
// ---------------------------------------------------------------------------
__global__ __launch_bounds__(256, 2) void k_em_slowfix(
    const float* __restrict__ xl, const float* __restrict__ binit,
    const float* __restrict__ xmp, short* __restrict__ featb,
    float* __restrict__ psum, float* __restrict__ pmax,
    const int* __restrict__ flag) {
  const int bid = blockIdx.x;
  if (flag[bid] == 0) return;
  __shared__ float psL[1024], pmL[1024];
  const int t = threadIdx.x;
  const int lane = t & 63, w = t >> 6;
  const int m0 = bid * 16 + w * 4;
  float ps4[4] = {0.f, 0.f, 0.f, 0.f};
  float pm4[4] = {-1e30f, -1e30f, -1e30f, -1e30f};
  for (int p = 0; p < 4; ++p) {
    const int m = m0 + p;
    const float4 s4 = *(const float4*)(xl + (size_t)m * 256 + lane * 4);
    const float s[4] = {s4.x, s4.y, s4.z, s4.w};
    float b[16];
#pragma unroll
    for (int r = 0; r < 16; ++r) {
      const float v = binit[(size_t)m * 16 + r];
      b[r] = v / fmaxf(fabsf(v), 1e-12f);
    }
    float c[4][16];
#pragma unroll
    for (int i = 0; i < 4; ++i) {
      float mx = s[i] * b[0];
#pragma unroll
      for (int r = 1; r < 16; ++r) mx = fmaxf(mx, s[i] * b[r]);
      float sum = 0.f;
#pragma unroll
      for (int r = 0; r < 16; ++r) {
        const float e = __expf(s[i] * b[r] - mx);
        c[i][r] = e;
        sum += e;
      }
      const float inv = __fdividef(1.f, sum);
#pragma unroll
      for (int r = 0; r < 16; ++r) c[i][r] *= inv;
    }
    for (int step = 0; step < 6; ++step) {
      float red[32];
#pragma unroll
      for (int r = 0; r < 32; ++r) red[r] = 0.f;
#pragma unroll
      for (int i = 0; i < 4; ++i) {
        float tt = 0.f;
#pragma unroll
        for (int r = 0; r < 16; ++r) tt += c[i][r] * b[r];
        float tp = 0.f;
#pragma unroll
        for (int r = 0; r < 16; ++r) {
          const float cn = c[i][r] * (s[i] * b[r]) * __frcp_rn(tt * b[r] + EPS);
          c[i][r] = cn;
          tp += cn * b[r];
          red[r] += s[i] * cn;
        }
#pragma unroll
        for (int r = 0; r < 16; ++r) red[16 + r] += tp * c[i][r];
      }
      int cnt = 32;
#pragma unroll
      for (int k = 4; k >= 0; --k) {
        const int d = 1 << k;
        const bool up = (lane >> k) & 1;
        const int half = cnt >> 1;
#pragma unroll
        for (int j = 0; j < half; ++j) {
          const float lo = red[j], hi = red[j + half];
          const float send = up ? lo : hi;
          const float recv = __shfl_xor(send, d, 64);
          red[j] = (up ? hi : lo) + recv;
        }
        cnt = half;
      }
      float S = red[0] + __shfl_xor(red[0], 32, 64);
      const float dpart = __shfl_xor(S, 16, 64);
      const float q = S * __frcp_rn(dpart + EPS);
#pragma unroll
      for (int r = 0; r < 16; ++r) b[r] *= __shfl(q, r, 64);
    }
    const float4 xm4 = *(const float4*)(xmp + (size_t)m * 256 + lane * 4);
    const float xmv[4] = {xm4.x, xm4.y, xm4.z, xm4.w};
    float o4[4];
#pragma unroll
    for (int i = 0; i < 4; ++i) {
      float tt = 0.f;
#pragma unroll
      for (int r = 0; r < 16; ++r) tt += c[i][r] * b[r];
      float xr = 0.f;
#pragma unroll
      for (int r = 0; r < 16; ++r) {
        const float cn = c[i][r] * (s[i] * b[r]) * __frcp_rn(tt * b[r] + EPS);
        xr += b[r] * cn;
      }
      o4[i] = fmaxf(xmv[i] + xr, 0.f);
      ps4[i] += o4[i];
      pm4[i] = fmaxf(pm4[i], o4[i]);
    }
    short4 sv = {bf16of(o4[0]), bf16of(o4[1]), bf16of(o4[2]), bf16of(o4[3])};
    *(short4*)(featb + (size_t)m * 256 + lane * 4) = sv;
  }
#pragma unroll
  for (int i = 0; i < 4; ++i) {
    psL[w * 256 + lane * 4 + i] = ps4[i];
    pmL[w * 256 + lane * 4 + i] = pm4[i];
  }
  __syncthreads();
  const float sv = psL[t] + psL[256 + t] + psL[512 + t] + psL[768 + t];
  const float mv =
      fmaxf(fmaxf(pmL[t], pmL[256 + t]), fmaxf(pmL[512 + t], pmL[768 + t]));
  psum[(size_t)bid * 256 + t] = sv;
  pmax[(size_t)bid * 256 + t] = mv;
}

// ---------------------------------------------------------------------------
// K6: finish pooling (256 chunks/img, 4-way parallel) + CA MLP + sigmoid.
// ---------------------------------------------------------------------------
__global__ __launch_bounds__(1024) void k_att(const float* __restrict__ psum,
                                              const float* __restrict__ pmax,
                                              const float* __restrict__ ca1,
                                              const float* __restrict__ ca2,
                                              float* __restrict__ attv,
                                              float* __restrict__ out_att) {
  __shared__ float sA[4][256], sM[4][256], fA[256], fM[256], sH[64];
  const int t = threadIdx.x;
  const int b = blockIdx.x;
  const int ch = t & 255, part = t >> 8;
  float sum = 0.f, mx = -1e30f;
#pragma unroll 4
  for (int j = 0; j < 64; ++j) {
    const int g = b * 256 + part * 64 + j;
    sum += psum[(size_t)g * 256 + ch];
    mx = fmaxf(mx, pmax[(size_t)g * 256 + ch]);
  }
  sA[part][ch] = sum;
  sM[part][ch] = mx;
  __syncthreads();
  if (t < 256) {
    fA[t] = (sA[0][t] + sA[1][t] + sA[2][t] + sA[3][t]) * (1.0f / 4096.0f);
    fM[t] = fmaxf(fmaxf(sM[0][t], sM[1][t]), fmaxf(sM[2][t], sM[3][t]));
  }
  __syncthreads();
  if (t < 64) {
    float ha = 0.f, hm = 0.f;
#pragma unroll 8
    for (int p = 0; p < 256; ++p) {
      const float wv = ca1[t * 256 + p];
      ha += fA[p] * wv;
      hm += fM[p] * wv;
    }
    sH[t] = fmaxf(ha, 0.f) + fmaxf(hm, 0.f);
  }
  __syncthreads();
  if (t < 256) {
    float logit = 0.f;
#pragma unroll 8
    for (int a = 0; a < 64; ++a) logit += sH[a] * ca2[t * 64 + a];
    const float av = 1.0f / (1.0f + expf(-logit));
    attv[b * 256 + t] = av;
    out_att[b * 256 + t] = av;
  }
}

// ---------------------------------------------------------------------------
// K7 (MFMA): out = (feat*att) @ fw^T + fb.  feat input bf16.
// ---------------------------------------------------------------------------
__global__ __launch_bounds__(256) void k_fc(const unsigned short* __restrict__ featb,
                                            const float* __restrict__ attv,
                                            const float* __restrict__ fw,
                                            const float* __restrict__ fb,
                                            float* __restrict__ out) {
  __shared__ __align__(16) short Fs[64 * PITCH];   // [m][k]
  __shared__ __align__(16) short Ws[128 * PITCH];  // [o][k]
  const int t = threadIdx.x;
  const int m0 = blockIdx.x * 64;
  const int img = m0 >> 12, hw0 = m0 & 4095;
  const int lane = t & 63, w = t >> 6;
  const int lrow = lane & 15, lk = (lane >> 4) * 8;
  f32x4 acc[2][4];
#pragma unroll
  for (int i = 0; i < 2; ++i)
#pragma unroll
    for (int j = 0; j < 4; ++j) acc[i][j] = {0.f, 0.f, 0.f, 0.f};

  for (int kk = 0; kk < 256; kk += 64) {
    __syncthreads();
    {
      const int m = t & 63, q = t >> 6;
      const unsigned short* fp = featb + (size_t)(m0 + m) * 256 + kk + q * 16;
      const float* ap = attv + img * 256 + kk + q * 16;
#pragma unroll
      for (int jj = 0; jj < 4; ++jj) {
        const ushort4 v = *(const ushort4*)(fp + jj * 4);
        const float4 a = *(const float4*)(ap + jj * 4);
        short4 sv = {bf16of(f32of(v.x) * a.x), bf16of(f32of(v.y) * a.y),
                     bf16of(f32of(v.z) * a.z), bf16of(f32of(v.w) * a.w)};
        *(short4*)(&Fs[m * PITCH + q * 16 + jj * 4]) = sv;
      }
    }
    {
      const int o = t & 127, q = t >> 7;
      const float* wp = fw + (size_t)o * 256 + kk + q * 32;
#pragma unroll
      for (int jj = 0; jj < 8; ++jj) {
        const float4 v = *(const float4*)(wp + jj * 4);
        short4 sv = {bf16of(v.x), bf16of(v.y), bf16of(v.z), bf16of(v.w)};
        *(short4*)(&Ws[o * PITCH + q * 32 + jj * 4]) = sv;
      }
    }
    __syncthreads();
#pragma unroll
    for (int ks = 0; ks < 2; ++ks) {
      const int ko = ks * 32 + lk;
      s16x8 af[2];
#pragma unroll
      for (int i = 0; i < 2; ++i)
        af[i] = *(const s16x8*)(&Fs[(((w & 1) * 2 + i) * 16 + lrow) * PITCH + ko]);
#pragma unroll
      for (int j = 0; j < 4; ++j) {
        const s16x8 bfr = *(const s16x8*)(&Ws[(((w >> 1) * 4 + j) * 16 + lrow) * PITCH + ko]);
#pragma unroll
        for (int i = 0; i < 2; ++i)
          acc[i][j] = __builtin_amdgcn_mfma_f32_16x16x32_bf16(af[i], bfr, acc[i][j], 0, 0, 0);
      }
    }
  }
#pragma unroll
  for (int j = 0; j < 4; ++j) {
    const int o = ((w >> 1) * 4 + j) * 16 + lrow;
    const float bias = fb[o];
#pragma unroll
    for (int i = 0; i < 2; ++i) {
      const int hw = hw0 + ((w & 1) * 2 + i) * 16 + (lane >> 4) * 4;
      f32x4 v = acc[i][j];
      v.x += bias;
      v.y += bias;
      v.z += bias;
      v.w += bias;
      *(f32x4*)(out + (size_t)img * 524288 + (size_t)o * 4096 + hw) = v;
    }
  }
}

extern "C" void kernel_launch(void* const* d_in, const int* in_sizes, int n_in,
                              void* d_out, int out_size, void* d_ws, size_t ws_size,
                              hipStream_t stream) {
  const float* x = (const float*)d_in[0];
  const float* w1 = (const float*)d_in[1];
  const float* w3 = (const float*)d_in[2];
  const float* b3 = (const float*)d_in[3];
  const float* lw = (const float*)d_in[4];
  const float* lb = (const float*)d_in[5];
  const float* ca1 = (const float*)d_in[6];
  const float* ca2 = (const float*)d_in[7];
  const float* fw = (const float*)d_in[8];
  const float* fb = (const float*)d_in[9];
  const float* binit = (const float*)d_in[10];

  char* wsb = (char*)d_ws;
  float* xm = (float*)wsb;                          // 16 MB fp32
  float* xl = (float*)(wsb + (16u << 20));          // 16 MB fp32
  short* ybf = (short*)(wsb + (32u << 20));         // 8 MB bf16
  short* featb = (short*)(wsb + (42u << 20));       // 8 MB bf16
  float* psum = (float*)(wsb + (52u << 20));        // 1 MB
  float* pmax = (float*)(wsb + (54u << 20));        // 1 MB
  float* attv = (float*)(wsb + (56u << 20));        // 4 KB
  int* flag = (int*)(wsb + (57u << 20));            // 4 KB
  float* out = (float*)d_out;
  float* out_att = out + 2097152;

  const dim3 blk(256);
  k_conv1x1<<<dim3(256), blk, 0, stream>>>(x, w1, ybf);
  k_dwconv<<<dim3(4096), blk, 0, stream>>>((const unsigned short*)ybf, w3, b3, xm);
  k_lower<<<dim3(256), blk, 0, stream>>>(xm, lw, lb, xl);
  k_em_fast<<<dim3(1024), blk, 0, stream>>>(xl, binit, xm, featb, psum, pmax, flag);
  k_em_slowfix<<<dim3(1024), blk, 0, stream>>>(xl, binit, xm, featb, psum, pmax, flag);
  k_att<<<dim3(4), dim3(1024), 0, stream>>>(psum, pmax, ca1, ca2, attv, out_att);
  k_fc<<<dim3(256), blk, 0, stream>>>((const unsigned short*)featb, attv, fw, fb, out);
}

// Round 8
// 88.361 us; speedup vs baseline: 1.2532x; 1.0689x over previous
//
#include <hip/hip_runtime.h>
#include <hip/hip_bf16.h>
#include <math.h>

#define EPS 1e-6f
#define PITCH 72  // bf16 elems per LDS row: 64 K + 8 pad (2-way bank conflict = free)

typedef short s16x8 __attribute__((ext_vector_type(8)));
typedef float f32x4 __attribute__((ext_vector_type(4)));

__device__ __forceinline__ short bf16of(float f) {
  __hip_bfloat16 h = __float2bfloat16(f);
  return __builtin_bit_cast(short, h);
}
__device__ __forceinline__ float f32of(unsigned short u) {
  unsigned int x = ((unsigned int)u) << 16;
  return __builtin_bit_cast(float, x);
}

// ---------------------------------------------------------------------------
// K1 (MFMA): y[m][p] = sum_c x[img][c][hw] * w1[p][c].  Output bf16.
// 64m x 128p per block, grid (256 m-tiles, 2 p-halves) = 2 blocks/CU.
// ---------------------------------------------------------------------------
__global__ __launch_bounds__(256) void k_conv1x1(const float* __restrict__ x,
                                                 const float* __restrict__ w1,
                                                 short* __restrict__ ybf) {
  __shared__ __align__(16) short Aw[128 * PITCH];  // [p][k]
  __shared__ __align__(16) short Xs[64 * PITCH];   // [m][k]
  const int t = threadIdx.x;
  const int m0 = blockIdx.x * 64, p0 = blockIdx.y * 128;
  const int img = m0 >> 12, hw0 = m0 & 4095;
  const int lane = t & 63, w = t >> 6;
  const int lrow = lane & 15, lk = (lane >> 4) * 8;
  f32x4 acc[4][2];
#pragma unroll
  for (int i = 0; i < 4; ++i)
#pragma unroll
    for (int j = 0; j < 2; ++j) acc[i][j] = {0.f, 0.f, 0.f, 0.f};

  for (int kk = 0; kk < 128; kk += 64) {
    __syncthreads();
    {  // stage w1 rows p0..p0+127, 32 k-elems per thread
      const int pr = t & 127, kq = t >> 7;
      const float* wp = w1 + (size_t)(p0 + pr) * 128 + kk + kq * 32;
#pragma unroll
      for (int q = 0; q < 8; ++q) {
        const float4 v = *(const float4*)(wp + q * 4);
        short4 sv = {bf16of(v.x), bf16of(v.y), bf16of(v.z), bf16of(v.w)};
        *(short4*)(&Aw[pr * PITCH + kq * 32 + q * 4]) = sv;
      }
    }
    {  // stage x (c-major) -> Xs[m][c]: 4x4 register transpose
      const int m4 = (t & 15) * 4;
      const int cg = (t >> 4) * 4;
      float4 col[4];
#pragma unroll
      for (int cc = 0; cc < 4; ++cc)
        col[cc] = *(const float4*)(x + (size_t)(img * 128 + kk + cg + cc) * 4096 + hw0 + m4);
#pragma unroll
      for (int r = 0; r < 4; ++r) {
        short4 sv = {bf16of(((const float*)&col[0])[r]),
                     bf16of(((const float*)&col[1])[r]),
                     bf16of(((const float*)&col[2])[r]),
                     bf16of(((const float*)&col[3])[r])};
        *(short4*)(&Xs[(m4 + r) * PITCH + cg]) = sv;
      }
    }
    __syncthreads();
#pragma unroll
    for (int ks = 0; ks < 2; ++ks) {
      const int ko = ks * 32 + lk;
      s16x8 bfr[2];
#pragma unroll
      for (int j = 0; j < 2; ++j)
        bfr[j] = *(const s16x8*)(&Xs[(((w >> 1) * 2 + j) * 16 + lrow) * PITCH + ko]);
#pragma unroll
      for (int i = 0; i < 4; ++i) {
        const s16x8 af = *(const s16x8*)(&Aw[(((w & 1) * 4 + i) * 16 + lrow) * PITCH + ko]);
#pragma unroll
        for (int j = 0; j < 2; ++j)
          acc[i][j] = __builtin_amdgcn_mfma_f32_16x16x32_bf16(af, bfr[j], acc[i][j], 0, 0, 0);
      }
    }
  }
#pragma unroll
  for (int i = 0; i < 4; ++i) {
    const int p = p0 + ((w & 1) * 4 + i) * 16 + (lane >> 4) * 4;
#pragma unroll
    for (int j = 0; j < 2; ++j) {
      const int m = m0 + ((w >> 1) * 2 + j) * 16 + lrow;
      const f32x4 v = acc[i][j];
      short4 sv = {bf16of(v.x), bf16of(v.y), bf16of(v.z), bf16of(v.w)};
      *(short4*)(ybf + (size_t)m * 256 + p) = sv;
    }
  }
}

// ---------------------------------------------------------------------------
// K2: depthwise 3x3 SAME + bias; bf16 in, bf16 out (round at write).
// ---------------------------------------------------------------------------
__global__ __launch_bounds__(256) void k_dwconv(const unsigned short* __restrict__ ybf,
                                                const float* __restrict__ w3,
                                                const float* __restrict__ b3,
                                                short* __restrict__ xmb) {
  __shared__ float wt[9][256];
  __shared__ float bs[256];
  const int t = threadIdx.x;
#pragma unroll
  for (int i = 0; i < 9; ++i) wt[i][t] = w3[t * 9 + i];
  bs[t] = b3[t];
  __syncthreads();
  const int sub = t >> 6;
  const int pq = t & 63;
  const int m = blockIdx.x * 4 + sub;
  const int hw = m & 4095;
  const int h = hw >> 6, ww = hw & 63;
  const int bb = m >> 12;
  float4 acc = *(const float4*)(&bs[pq * 4]);
#pragma unroll
  for (int dy = -1; dy <= 1; ++dy) {
    const int hh = h + dy;
    if (hh < 0 || hh > 63) continue;
#pragma unroll
    for (int dx = -1; dx <= 1; ++dx) {
      const int w2 = ww + dx;
      if (w2 < 0 || w2 > 63) continue;
      const int idx = (dy + 1) * 3 + (dx + 1);
      const ushort4 v =
          *(const ushort4*)(ybf + (size_t)((bb << 12) + (hh << 6) + w2) * 256 + pq * 4);
      const float4 wv = *(const float4*)(&wt[idx][pq * 4]);
      acc.x += f32of(v.x) * wv.x;
      acc.y += f32of(v.y) * wv.y;
      acc.z += f32of(v.z) * wv.z;
      acc.w += f32of(v.w) * wv.w;
    }
  }
  short4 sv = {bf16of(acc.x), bf16of(acc.y), bf16of(acc.z), bf16of(acc.w)};
  *(short4*)(xmb + (size_t)m * 256 + pq * 4) = sv;
}

// ---------------------------------------------------------------------------
// K3 (MFMA): xl = relu(xm @ lw^T + lb).  xm bf16 in (direct LDS copy),
// xl bf16 out.  64m x 128n per block, grid (256, 2).
// ---------------------------------------------------------------------------
__global__ __launch_bounds__(256) void k_lower(const unsigned short* __restrict__ xmb,
                                               const float* __restrict__ lw,
                                               const float* __restrict__ lb,
                                               short* __restrict__ xlb) {
  __shared__ __align__(16) short Aw[128 * PITCH];  // [n][k]
  __shared__ __align__(16) short Xs[64 * PITCH];   // [m][k]
  const int t = threadIdx.x;
  const int m0 = blockIdx.x * 64, n0 = blockIdx.y * 128;
  const int lane = t & 63, w = t >> 6;
  const int lrow = lane & 15, lk = (lane >> 4) * 8;
  f32x4 acc[4][2];
#pragma unroll
  for (int i = 0; i < 4; ++i)
#pragma unroll
    for (int j = 0; j < 2; ++j) acc[i][j] = {0.f, 0.f, 0.f, 0.f};

  for (int kk = 0; kk < 256; kk += 64) {
    __syncthreads();
    {  // stage lw rows n0..n0+127
      const int nr = t & 127, kq = t >> 7;
      const float* wp = lw + (size_t)(n0 + nr) * 256 + kk + kq * 32;
#pragma unroll
      for (int q = 0; q < 8; ++q) {
        const float4 v = *(const float4*)(wp + q * 4);
        short4 sv = {bf16of(v.x), bf16of(v.y), bf16of(v.z), bf16of(v.w)};
        *(short4*)(&Aw[nr * PITCH + kq * 32 + q * 4]) = sv;
      }
    }
    {  // stage xm (already bf16) — straight copy
      const int m = t & 63, q = t >> 6;
      const unsigned short* xp = xmb + (size_t)(m0 + m) * 256 + kk + q * 16;
      *(s16x8*)(&Xs[m * PITCH + q * 16]) = *(const s16x8*)(xp);
      *(s16x8*)(&Xs[m * PITCH + q * 16 + 8]) = *(const s16x8*)(xp + 8);
    }
    __syncthreads();
#pragma unroll
    for (int ks = 0; ks < 2; ++ks) {
      const int ko = ks * 32 + lk;
      s16x8 bfr[2];
#pragma unroll
      for (int j = 0; j < 2; ++j)
        bfr[j] = *(const s16x8*)(&Xs[(((w >> 1) * 2 + j) * 16 + lrow) * PITCH + ko]);
#pragma unroll
      for (int i = 0; i < 4; ++i) {
        const s16x8 af = *(const s16x8*)(&Aw[(((w & 1) * 4 + i) * 16 + lrow) * PITCH + ko]);
#pragma unroll
        for (int j = 0; j < 2; ++j)
          acc[i][j] = __builtin_amdgcn_mfma_f32_16x16x32_bf16(af, bfr[j], acc[i][j], 0, 0, 0);
      }
    }
  }
#pragma unroll
  for (int i = 0; i < 4; ++i) {
    const int n = n0 + ((w & 1) * 4 + i) * 16 + (lane >> 4) * 4;
    const float4 bias = *(const float4*)(lb + n);
#pragma unroll
    for (int j = 0; j < 2; ++j) {
      const int m = m0 + ((w >> 1) * 2 + j) * 16 + lrow;
      const f32x4 v = acc[i][j];
      short4 sv = {bf16of(fmaxf(v.x + bias.x, 0.f)), bf16of(fmaxf(v.y + bias.y, 0.f)),
                   bf16of(fmaxf(v.z + bias.z, 0.f)), bf16of(fmaxf(v.w + bias.w, 0.f))};
      *(short4*)(xlb + (size_t)m * 256 + n) = sv;
    }
  }
}

// ---------------------------------------------------------------------------
// K4a: fast EM, 16 px/block (4/wave, lockstep ILP-4), fused pooling.
// bf16 xl/xm in, bf16 feat out; pool partials fp32 (pre-rounding).
// ---------------------------------------------------------------------------
__global__ __launch_bounds__(256) void k_em_fast(const unsigned short* __restrict__ xlb,
                                                 const float* __restrict__ binit,
                                                 const unsigned short* __restrict__ xmb,
                                                 short* __restrict__ featb,
                                                 float* __restrict__ psum,
                                                 float* __restrict__ pmax,
                                                 int* __restrict__ flag) {
  __shared__ float psL[1024], pmL[1024];
  __shared__ int sflag;
  const int t = threadIdx.x;
  const int lane = t & 63, w = t >> 6;
  const int bid = blockIdx.x;
  const int m0 = bid * 16 + w * 4;
  bool asym = false;
#pragma unroll
  for (int p = 0; p < 4; ++p) {
    const float bv = binit[(size_t)(m0 + p) * 16 + (lane & 15)];
    const float bn = bv / fmaxf(fabsf(bv), 1e-12f);
    asym |= !__all(bn == 1.0f);
  }
  if (t == 0) sflag = 0;
  __syncthreads();
  if (asym && lane == 0) sflag = 1;
  __syncthreads();
  if (sflag) {
    if (t == 0) flag[bid] = 1;
    return;
  }

  float s[4][4], C[4][4], Bv[4];
#pragma unroll
  for (int p = 0; p < 4; ++p) {
    const ushort4 su = *(const ushort4*)(xlb + (size_t)(m0 + p) * 256 + lane * 4);
    s[p][0] = f32of(su.x);
    s[p][1] = f32of(su.y);
    s[p][2] = f32of(su.z);
    s[p][3] = f32of(su.w);
    Bv[p] = 1.f;
#pragma unroll
    for (int i = 0; i < 4; ++i) C[p][i] = 0.0625f;
  }
  for (int step = 0; step < 6; ++step) {
    float pnum[4], psq[4];
#pragma unroll
    for (int p = 0; p < 4; ++p) {
      const float k1 = 16.f * Bv[p] * Bv[p];
      pnum[p] = 0.f;
      psq[p] = 0.f;
#pragma unroll
      for (int i = 0; i < 4; ++i) {
        const float den = fmaf(C[p][i], k1, EPS);
        const float cn = C[p][i] * (s[p][i] * Bv[p]) * __builtin_amdgcn_rcpf(den);
        C[p][i] = cn;
        pnum[p] = fmaf(s[p][i], cn, pnum[p]);
        psq[p] = fmaf(cn, cn, psq[p]);
      }
    }
#pragma unroll
    for (int d = 1; d < 64; d <<= 1) {
#pragma unroll
      for (int p = 0; p < 4; ++p) {
        pnum[p] += __shfl_xor(pnum[p], d, 64);
        psq[p] += __shfl_xor(psq[p], d, 64);
      }
    }
#pragma unroll
    for (int p = 0; p < 4; ++p)
      Bv[p] = Bv[p] * pnum[p] *
              __builtin_amdgcn_rcpf(fmaf(16.f * Bv[p], psq[p], EPS));
  }
  float ps4[4] = {0.f, 0.f, 0.f, 0.f};
  float pm4[4] = {-1e30f, -1e30f, -1e30f, -1e30f};
#pragma unroll
  for (int p = 0; p < 4; ++p) {
    const ushort4 xmu = *(const ushort4*)(xmb + (size_t)(m0 + p) * 256 + lane * 4);
    const float xmv[4] = {f32of(xmu.x), f32of(xmu.y), f32of(xmu.z), f32of(xmu.w)};
    const float k1 = 16.f * Bv[p] * Bv[p];
    float o[4];
#pragma unroll
    for (int i = 0; i < 4; ++i) {
      const float den = fmaf(C[p][i], k1, EPS);
      const float cn = C[p][i] * (s[p][i] * Bv[p]) * __builtin_amdgcn_rcpf(den);
      const float xr = 16.f * Bv[p] * cn;
      o[i] = fmaxf(xmv[i] + xr, 0.f);
      ps4[i] += o[i];
      pm4[i] = fmaxf(pm4[i], o[i]);
    }
    short4 sv = {bf16of(o[0]), bf16of(o[1]), bf16of(o[2]), bf16of(o[3])};
    *(short4*)(featb + (size_t)(m0 + p) * 256 + lane * 4) = sv;
  }
#pragma unroll
  for (int i = 0; i < 4; ++i) {
    psL[w * 256 + lane * 4 + i] = ps4[i];
    pmL[w * 256 + lane * 4 + i] = pm4[i];
  }
  __syncthreads();
  const float sv = psL[t] + psL[256 + t] + psL[512 + t] + psL[768 + t];
  const float mv =
      fmaxf(fmaxf(pmL[t], pmL[256 + t]), fmaxf(pmL[512 + t], pmL[768 + t]));
  psum[(size_t)bid * 256 + t] = sv;
  pmax[(size_t)bid * 256 + t] = mv;
  if (t == 0) flag[bid] = 0;
}

// ---------------------------------------------------------------------------
// K4b: flag-gated general-EM recompute of a 16-pixel chunk (bf16 in/out).
// ---------------------------------------------------------------------------
__global__ __launch_bounds__(256, 2) void k_em_slowfix(
    const unsigned short* __restrict__ xlb, const float* __restrict__ binit,
    const unsigned short* __restrict__ xmb, short* __restrict__ featb,
    float* __restrict__ psum, float* __restrict__ pmax,
    const int* __restrict__ flag) {
  const int bid = blockIdx.x;
  if (flag[bid] == 0) return;
  __shared__ float psL[1024], pmL[1024];
  const int t = threadIdx.x;
  const int lane = t & 63, w = t >> 6;
  const int m0 = bid * 16 + w * 4;
  float ps4[4] = {0.f, 0.f, 0.f, 0.f};
  float pm4[4] = {-1e30f, -1e30f, -1e30f, -1e30f};
  for (int p = 0; p < 4; ++p) {
    const int m = m0 + p;
    const ushort4 su = *(const ushort4*)(xlb + (size_t)m * 256 + lane * 4);
    const float s[4] = {f32of(su.x), f32of(su.y), f32of(su.z), f32of(su.w)};
    float b[16];
#pragma unroll
    for (int r = 0; r < 16; ++r) {
      const float v = binit[(size_t)m * 16 + r];
      b[r] = v / fmaxf(fabsf(v), 1e-12f);
    }
    float c[4][16];
#pragma unroll
    for (int i = 0; i < 4; ++i) {
      float mx = s[i] * b[0];
#pragma unroll
      for (int r = 1; r < 16; ++r) mx = fmaxf(mx, s[i] * b[r]);
      float sum = 0.f;
#pragma unroll
      for (int r = 0; r < 16; ++r) {
        const float e = __expf(s[i] * b[r] - mx);
        c[i][r] = e;
        sum += e;
      }
      const float inv = __fdividef(1.f, sum);
#pragma unroll
      for (int r = 0; r < 16; ++r) c[i][r] *= inv;
    }
    for (int step = 0; step < 6; ++step) {
      float red[32];
#pragma unroll
      for (int r = 0; r < 32; ++r) red[r] = 0.f;
#pragma unroll
      for (int i = 0; i < 4; ++i) {
        float tt = 0.f;
#pragma unroll
        for (int r = 0; r < 16; ++r) tt += c[i][r] * b[r];
        float tp = 0.f;
#pragma unroll
        for (int r = 0; r < 16; ++r) {
          const float cn = c[i][r] * (s[i] * b[r]) * __frcp_rn(tt * b[r] + EPS);
          c[i][r] = cn;
          tp += cn * b[r];
          red[r] += s[i] * cn;
        }
#pragma unroll
        for (int r = 0; r < 16; ++r) red[16 + r] += tp * c[i][r];
      }
      int cnt = 32;
#pragma unroll
      for (int k = 4; k >= 0; --k) {
        const int d = 1 << k;
        const bool up = (lane >> k) & 1;
        const int half = cnt >> 1;
#pragma unroll
        for (int j = 0; j < half; ++j) {
          const float lo = red[j], hi = red[j + half];
          const float send = up ? lo : hi;
          const float recv = __shfl_xor(send, d, 64);
          red[j] = (up ? hi : lo) + recv;
        }
        cnt = half;
      }
      float S = red[0] + __shfl_xor(red[0], 32, 64);
      const float dpart = __shfl_xor(S, 16, 64);
      const float q = S * __frcp_rn(dpart + EPS);
#pragma unroll
      for (int r = 0; r < 16; ++r) b[r] *= __shfl(q, r, 64);
    }
    const ushort4 xmu = *(const ushort4*)(xmb + (size_t)m * 256 + lane * 4);
    const float xmv[4] = {f32of(xmu.x), f32of(xmu.y), f32of(xmu.z), f32of(xmu.w)};
    float o4[4];
#pragma unroll
    for (int i = 0; i < 4; ++i) {
      float tt = 0.f;
#pragma unroll
      for (int r = 0; r < 16; ++r) tt += c[i][r] * b[r];
      float xr = 0.f;
#pragma unroll
      for (int r = 0; r < 16; ++r) {
        const float cn = c[i][r] * (s[i] * b[r]) * __frcp_rn(tt * b[r] + EPS);
        xr += b[r] * cn;
      }
      o4[i] = fmaxf(xmv[i] + xr, 0.f);
      ps4[i] += o4[i];
      pm4[i] = fmaxf(pm4[i], o4[i]);
    }
    short4 sv = {bf16of(o4[0]), bf16of(o4[1]), bf16of(o4[2]), bf16of(o4[3])};
    *(short4*)(featb + (size_t)m * 256 + lane * 4) = sv;
  }
#pragma unroll
  for (int i = 0; i < 4; ++i) {
    psL[w * 256 + lane * 4 + i] = ps4[i];
    pmL[w * 256 + lane * 4 + i] = pm4[i];
  }
  __syncthreads();
  const float sv = psL[t] + psL[256 + t] + psL[512 + t] + psL[768 + t];
  const float mv =
      fmaxf(fmaxf(pmL[t], pmL[256 + t]), fmaxf(pmL[512 + t], pmL[768 + t]));
  psum[(size_t)bid * 256 + t] = sv;
  pmax[(size_t)bid * 256 + t] = mv;
}

// ---------------------------------------------------------------------------
// K6: finish pooling + CA MLP + sigmoid (unchanged).
// ---------------------------------------------------------------------------
__global__ __launch_bounds__(1024) void k_att(const float* __restrict__ psum,
                                              const float* __restrict__ pmax,
                                              const float* __restrict__ ca1,
                                              const float* __restrict__ ca2,
                                              float* __restrict__ attv,
                                              float* __restrict__ out_att) {
  __shared__ float sA[4][256], sM[4][256], fA[256], fM[256], sH[64];
  const int t = threadIdx.x;
  const int b = blockIdx.x;
  const int ch = t & 255, part = t >> 8;
  float sum = 0.f, mx = -1e30f;
#pragma unroll 4
  for (int j = 0; j < 64; ++j) {
    const int g = b * 256 + part * 64 + j;
    sum += psum[(size_t)g * 256 + ch];
    mx = fmaxf(mx, pmax[(size_t)g * 256 + ch]);
  }
  sA[part][ch] = sum;
  sM[part][ch] = mx;
  __syncthreads();
  if (t < 256) {
    fA[t] = (sA[0][t] + sA[1][t] + sA[2][t] + sA[3][t]) * (1.0f / 4096.0f);
    fM[t] = fmaxf(fmaxf(sM[0][t], sM[1][t]), fmaxf(sM[2][t], sM[3][t]));
  }
  __syncthreads();
  if (t < 64) {
    float ha = 0.f, hm = 0.f;
#pragma unroll 8
    for (int p = 0; p < 256; ++p) {
      const float wv = ca1[t * 256 + p];
      ha += fA[p] * wv;
      hm += fM[p] * wv;
    }
    sH[t] = fmaxf(ha, 0.f) + fmaxf(hm, 0.f);
  }
  __syncthreads();
  if (t < 256) {
    float logit = 0.f;
#pragma unroll 8
    for (int a = 0; a < 64; ++a) logit += sH[a] * ca2[t * 64 + a];
    const float av = 1.0f / (1.0f + expf(-logit));
    attv[b * 256 + t] = av;
    out_att[b * 256 + t] = av;
  }
}

// ---------------------------------------------------------------------------
// K7 (MFMA): out = (feat*att) @ fw^T + fb.  64m x 64o per block, grid (256,2).
// ---------------------------------------------------------------------------
__global__ __launch_bounds__(256) void k_fc(const unsigned short* __restrict__ featb,
                                            const float* __restrict__ attv,
                                            const float* __restrict__ fw,
                                            const float* __restrict__ fb,
                                            float* __restrict__ out) {
  __shared__ __align__(16) short Fs[64 * PITCH];  // [m][k]
  __shared__ __align__(16) short Ws[64 * PITCH];  // [o][k]
  const int t = threadIdx.x;
  const int m0 = blockIdx.x * 64, o0 = blockIdx.y * 64;
  const int img = m0 >> 12, hw0 = m0 & 4095;
  const int lane = t & 63, w = t >> 6;
  const int lrow = lane & 15, lk = (lane >> 4) * 8;
  f32x4 acc[2][2];  // [m-frag][o-frag]
#pragma unroll
  for (int i = 0; i < 2; ++i)
#pragma unroll
    for (int j = 0; j < 2; ++j) acc[i][j] = {0.f, 0.f, 0.f, 0.f};

  for (int kk = 0; kk < 256; kk += 64) {
    __syncthreads();
    {  // stage feat * att
      const int m = t & 63, q = t >> 6;
      const unsigned short* fp = featb + (size_t)(m0 + m) * 256 + kk + q * 16;
      const float* ap = attv + img * 256 + kk + q * 16;
#pragma unroll
      for (int jj = 0; jj < 4; ++jj) {
        const ushort4 v = *(const ushort4*)(fp + jj * 4);
        const float4 a = *(const float4*)(ap + jj * 4);
        short4 sv = {bf16of(f32of(v.x) * a.x), bf16of(f32of(v.y) * a.y),
                     bf16of(f32of(v.z) * a.z), bf16of(f32of(v.w) * a.w)};
        *(short4*)(&Fs[m * PITCH + q * 16 + jj * 4]) = sv;
      }
    }
    {  // stage fw rows o0..o0+63
      const int o = t & 63, q = t >> 6;
      const float* wp = fw + (size_t)(o0 + o) * 256 + kk + q * 16;
#pragma unroll
      for (int jj = 0; jj < 4; ++jj) {
        const float4 v = *(const float4*)(wp + jj * 4);
        short4 sv = {bf16of(v.x), bf16of(v.y), bf16of(v.z), bf16of(v.w)};
        *(short4*)(&Ws[o * PITCH + q * 16 + jj * 4]) = sv;
      }
    }
    __syncthreads();
#pragma unroll
    for (int ks = 0; ks < 2; ++ks) {
      const int ko = ks * 32 + lk;
      s16x8 af[2];
#pragma unroll
      for (int i = 0; i < 2; ++i)
        af[i] = *(const s16x8*)(&Fs[(((w >> 1) * 2 + i) * 16 + lrow) * PITCH + ko]);
#pragma unroll
      for (int j = 0; j < 2; ++j) {
        const s16x8 bfr = *(const s16x8*)(&Ws[(((w & 1) * 2 + j) * 16 + lrow) * PITCH + ko]);
#pragma unroll
        for (int i = 0; i < 2; ++i)
          acc[i][j] = __builtin_amdgcn_mfma_f32_16x16x32_bf16(af[i], bfr, acc[i][j], 0, 0, 0);
      }
    }
  }
#pragma unroll
  for (int j = 0; j < 2; ++j) {
    const int o = o0 + ((w & 1) * 2 + j) * 16 + lrow;
    const float bias = fb[o];
#pragma unroll
    for (int i = 0; i < 2; ++i) {
      const int hw = hw0 + ((w >> 1) * 2 + i) * 16 + (lane >> 4) * 4;
      f32x4 v = acc[i][j];
      v.x += bias;
      v.y += bias;
      v.z += bias;
      v.w += bias;
      *(f32x4*)(out + (size_t)img * 524288 + (size_t)o * 4096 + hw) = v;
    }
  }
}

extern "C" void kernel_launch(void* const* d_in, const int* in_sizes, int n_in,
                              void* d_out, int out_size, void* d_ws, size_t ws_size,
                              hipStream_t stream) {
  const float* x = (const float*)d_in[0];
  const float* w1 = (const float*)d_in[1];
  const float* w3 = (const float*)d_in[2];
  const float* b3 = (const float*)d_in[3];
  const float* lw = (const float*)d_in[4];
  const float* lb = (const float*)d_in[5];
  const float* ca1 = (const float*)d_in[6];
  const float* ca2 = (const float*)d_in[7];
  const float* fw = (const float*)d_in[8];
  const float* fb = (const float*)d_in[9];
  const float* binit = (const float*)d_in[10];

  char* wsb = (char*)d_ws;
  short* ybf = (short*)wsb;                      // 8 MB bf16
  short* xmb = (short*)(wsb + (8u << 20));       // 8 MB bf16
  short* xlb = (short*)(wsb + (16u << 20));      // 8 MB bf16
  short* featb = (short*)(wsb + (24u << 20));    // 8 MB bf16
  float* psum = (float*)(wsb + (32u << 20));     // 1 MB
  float* pmax = (float*)(wsb + (34u << 20));     // 1 MB
  float* attv = (float*)(wsb + (36u << 20));     // 4 KB
  int* flag = (int*)(wsb + (37u << 20));         // 4 KB
  float* out = (float*)d_out;
  float* out_att = out + 2097152;

  const dim3 blk(256);
  k_conv1x1<<<dim3(256, 2), blk, 0, stream>>>(x, w1, ybf);
  k_dwconv<<<dim3(4096), blk, 0, stream>>>((const unsigned short*)ybf, w3, b3, xmb);
  k_lower<<<dim3(256, 2), blk, 0, stream>>>((const unsigned short*)xmb, lw, lb, xlb);
  k_em_fast<<<dim3(1024), blk, 0, stream>>>((const unsigned short*)xlb, binit,
                                            (const unsigned short*)xmb, featb,
                                            psum, pmax, flag);
  k_em_slowfix<<<dim3(1024), blk, 0, stream>>>((const unsigned short*)xlb, binit,
                                               (const unsigned short*)xmb, featb,
                                               psum, pmax, flag);
  k_att<<<dim3(4), dim3(1024), 0, stream>>>(psum, pmax, ca1, ca2, attv, out_att);
  k_fc<<<dim3(256, 2), blk, 0, stream>>>((const unsigned short*)featb, attv, fw,
                                         fb, out);
}